// Round 5
// baseline (438.267 us; speedup 1.0000x reference)
//
#include <hip/hip_runtime.h>
#include <stdint.h>

#define RMS_EPS 1.1920929e-07f
#define EPS_LIN 1e-6f

typedef __attribute__((ext_vector_type(8))) short bf16x8;
typedef __attribute__((ext_vector_type(4))) float f32x4;

__device__ __forceinline__ unsigned short f2bf(float f) {
  union { float f; unsigned int u; } v; v.f = f;
  unsigned int r = v.u + 0x7fffu + ((v.u >> 16) & 1u);
  return (unsigned short)(r >> 16);
}
__device__ __forceinline__ float bf2f(unsigned short s) {
  union { unsigned int u; float f; } v; v.u = ((unsigned int)s) << 16;
  return v.f;
}

// ---------------- fused init: weights f32->bf16 + rope table ----------------
// R10: x conversion dropped (QKV GEMM reads f32 x directly in A-staging).
// block partition: [0,3072) Wqkv | [3072,4096) Wout | [4096,4608) rope
__global__ __launch_bounds__(256) void k_init(
    const float* __restrict__ Wqkv, const float* __restrict__ Wout,
    unsigned short* __restrict__ wqkvb, unsigned short* __restrict__ woutb,
    float* __restrict__ cosT, float* __restrict__ sinT) {
  const int blk = blockIdx.x;
  const int t = threadIdx.x;
  if (blk < 4096) {
    const float* src;
    unsigned short* dst;
    int base;
    if (blk < 3072) { src = Wqkv; dst = wqkvb; base = blk; }
    else { src = Wout; dst = woutb; base = blk - 3072; }
    int i = (base * 256 + t) * 4;
    float4 v = *reinterpret_cast<const float4*>(src + i);
    ushort4 o = { f2bf(v.x), f2bf(v.y), f2bf(v.z), f2bf(v.w) };
    *reinterpret_cast<ushort4*>(dst + i) = o;
  } else {
    int idx = (blk - 4096) * 256 + t;
    int l = idx >> 5, i = idx & 31;
    float inv_freq = expf(-((float)(2 * i) / 64.0f) * logf(10000.0f));
    float ang = (float)l * inv_freq;
    cosT[idx] = cosf(ang);
    sinT[idx] = sinf(ang);
  }
}

// ---------------- async global->LDS 16B stage ----------------
__device__ __forceinline__ void stage16(const unsigned short* g, unsigned short* lds_base,
                                        int lane) {
#if __has_builtin(__builtin_amdgcn_global_load_lds)
  __builtin_amdgcn_global_load_lds(
      (const __attribute__((address_space(1))) unsigned int*)g,
      (__attribute__((address_space(3))) unsigned int*)lds_base, 16, 0, 0);
#else
  *reinterpret_cast<uint4*>(lds_base + lane * 8) = *reinterpret_cast<const uint4*>(g);
#endif
}

// ---------------- bf16 GEMM C = A(MxK) * B(NxK)^T + bias ----------------
// 128x128 tile, BK=64, XOR-swizzled LDS (0 conflicts, ~918 TF).
// R10: swizzle + split-K reverted (R9: FETCH 143->197MB, +11us — B-panel
// reuse across XCDs beats chunked A-locality; split-K was round-neutral).
// mode 0: A read DIRECTLY as f32 (x) — reg-staged: 2x float4 -> f2bf x8 ->
// ds_write_b128 into the same swizzled slot gload_lds would fill.
__global__ __launch_bounds__(256, 3) void k_gemm_bt(
    const float* __restrict__ Af, const unsigned short* __restrict__ A,
    const unsigned short* __restrict__ Bw,
    const float* __restrict__ bias, int M, int N, int K, int mode,
    unsigned short* __restrict__ qb, unsigned short* __restrict__ kb,
    unsigned short* __restrict__ vb, unsigned short* __restrict__ preb) {
  __shared__ unsigned short As[128 * 64];
  __shared__ unsigned short Bs[128 * 64];
  const int nt = N >> 7;
  const int bm = blockIdx.x / nt, bn = blockIdx.x % nt;
  const int m0 = bm << 7, n0 = bn << 7;
  const int t = threadIdx.x;
  const int wave = t >> 6, lane = t & 63;
  const int wr = wave >> 1, wc = wave & 1;
  const int quad = lane >> 4, m16 = lane & 15;

  const float* AfS[4];
  const unsigned short* ApS[4];
  const unsigned short* BpS[4];
  unsigned short* AlS[4];
  unsigned short* BlS[4];
#pragma unroll
  for (int s = 0; s < 4; ++s) {
    int u = wave * 256 + s * 64 + lane;
    int row = u >> 3;
    int ku = (u & 7) ^ (row & 7);
    AfS[s] = Af + (size_t)(m0 + row) * K + ku * 8;
    ApS[s] = A + (size_t)(m0 + row) * K + ku * 8;
    BpS[s] = Bw + (size_t)(n0 + row) * K + ku * 8;
    AlS[s] = As + (size_t)(wave * 256 + s * 64) * 8;
    BlS[s] = Bs + (size_t)(wave * 256 + s * 64) * 8;
  }

  int offA[4][2], offB[4][2];
#pragma unroll
  for (int i = 0; i < 4; ++i) {
    int rowA = wr * 64 + i * 16 + m16;
    int rowB = wc * 64 + i * 16 + m16;
#pragma unroll
    for (int ks = 0; ks < 2; ++ks) {
      int kuf = ks * 4 + quad;
      offA[i][ks] = (rowA * 8 + (kuf ^ (rowA & 7))) * 8;
      offB[i][ks] = (rowB * 8 + (kuf ^ (rowB & 7))) * 8;
    }
  }

  f32x4 acc[4][4] = {};

  for (int k0 = 0; k0 < K; k0 += 64) {
    if (mode == 0) {
#pragma unroll
      for (int s = 0; s < 4; ++s) {
        const float* p = AfS[s] + k0;
        float4 f0 = *reinterpret_cast<const float4*>(p);
        float4 f1 = *reinterpret_cast<const float4*>(p + 4);
        bf16x8 o;
        o[0] = (short)f2bf(f0.x); o[1] = (short)f2bf(f0.y);
        o[2] = (short)f2bf(f0.z); o[3] = (short)f2bf(f0.w);
        o[4] = (short)f2bf(f1.x); o[5] = (short)f2bf(f1.y);
        o[6] = (short)f2bf(f1.z); o[7] = (short)f2bf(f1.w);
        *reinterpret_cast<bf16x8*>(AlS[s] + lane * 8) = o;
        stage16(BpS[s] + k0, BlS[s], lane);
      }
    } else {
#pragma unroll
      for (int s = 0; s < 4; ++s) {
        stage16(ApS[s] + k0, AlS[s], lane);
        stage16(BpS[s] + k0, BlS[s], lane);
      }
    }
    __syncthreads();
#pragma unroll
    for (int ks = 0; ks < 2; ++ks) {
      bf16x8 fa[4], fb[4];
#pragma unroll
      for (int i = 0; i < 4; ++i)
        fa[i] = *reinterpret_cast<const bf16x8*>(As + offA[i][ks]);
#pragma unroll
      for (int j = 0; j < 4; ++j)
        fb[j] = *reinterpret_cast<const bf16x8*>(Bs + offB[j][ks]);
#pragma unroll
      for (int i = 0; i < 4; ++i)
#pragma unroll
        for (int j = 0; j < 4; ++j)
          acc[i][j] = __builtin_amdgcn_mfma_f32_16x16x32_bf16(fa[i], fb[j], acc[i][j], 0, 0, 0);
    }
    __syncthreads();
  }

#pragma unroll
  for (int i = 0; i < 4; ++i) {
    int rbase = m0 + wr * 64 + i * 16 + quad * 4;
#pragma unroll
    for (int j = 0; j < 4; ++j) {
      int col = n0 + wc * 64 + j * 16 + m16;
      float bc = bias[col];
#pragma unroll
      for (int r = 0; r < 4; ++r) {
        int row = rbase + r;
        float val = acc[i][j][r] + bc;
        unsigned short bv = f2bf(val);
        if (mode == 0) {
          if (col < 1024) {
            qb[(size_t)row * 1024 + col] = bv;
          } else if (col < 2048) {
            kb[(size_t)row * 1024 + (col - 1024)] = bv;
          } else {
            int h = (col - 2048) >> 6, d = col & 63;
            int b = row >> 12, l = row & 4095;
            vb[(((size_t)(b * 16 + h)) * 4096 + l) * 64 + d] = bv;
          }
        } else {
          preb[(size_t)row * N + col] = bv;
        }
      }
    }
  }
}

// ---------------- q/k rmsnorm + rope + relu (wave-per-row) ----------
// 16 contiguous elems per lane -> 2x b128 load + 2x b128 store per array.
__global__ __launch_bounds__(256) void k_qknorm(
    const unsigned short* __restrict__ qb, const unsigned short* __restrict__ kb,
    const float* __restrict__ gq, const float* __restrict__ gk,
    const float* __restrict__ cosT, const float* __restrict__ sinT,
    unsigned short* __restrict__ qfb, unsigned short* __restrict__ kfb) {
  const int wid = (blockIdx.x << 2) + (threadIdx.x >> 6);
  const int row = wid >> 1;
  const int which = wid & 1;
  const int lane = threadIdx.x & 63;
  const int l = row & 4095;
  const int b = row >> 12;
  const unsigned short* src = (which ? kb : qb) + (size_t)row * 1024 + lane * 16;
  const float* g = which ? gk : gq;
  unsigned short* dstb = which ? kfb : qfb;

  bf16x8 u0 = *reinterpret_cast<const bf16x8*>(src);
  bf16x8 u1 = *reinterpret_cast<const bf16x8*>(src + 8);
  float v[16];
  float ss = 0.f;
#pragma unroll
  for (int e = 0; e < 8; ++e) {
    v[e] = bf2f((unsigned short)u0[e]);
    v[8 + e] = bf2f((unsigned short)u1[e]);
  }
#pragma unroll
  for (int e = 0; e < 16; ++e) ss += v[e] * v[e];
#pragma unroll
  for (int off = 1; off < 64; off <<= 1) ss += __shfl_xor(ss, off, 64);
  const float sc = rsqrtf(ss * (1.0f / 1024.0f) + RMS_EPS);

  const float* gp = g + lane * 16;
  const float* cp = cosT + l * 32 + (lane & 3) * 8;
  const float* sp = sinT + l * 32 + (lane & 3) * 8;
  bf16x8 o0, o1;
#pragma unroll
  for (int p = 0; p < 8; ++p) {
    float cc = cp[p], sv = sp[p];
    float x0 = v[2 * p] * sc * gp[2 * p];
    float x1 = v[2 * p + 1] * sc * gp[2 * p + 1];
    float r0 = x0 * cc - x1 * sv;
    float r1 = x0 * sv + x1 * cc;
    unsigned short b0 = f2bf(fmaxf(r0, 0.f));
    unsigned short b1 = f2bf(fmaxf(r1, 0.f));
    if (p < 4) { o0[2 * p] = (short)b0; o0[2 * p + 1] = (short)b1; }
    else { o1[2 * (p - 4)] = (short)b0; o1[2 * (p - 4) + 1] = (short)b1; }
  }
  unsigned short* dp =
      dstb + (((size_t)(b * 16 + (lane >> 2))) * 4096 + l) * 64 + (lane & 3) * 16;
  *reinterpret_cast<bf16x8*>(dp) = o0;
  *reinterpret_cast<bf16x8*>(dp + 8) = o1;
}

// ---------------- vk[p][d] = sum_l vpad[l][p]*kf[l][d] (per bh) -- MFMA ----------
// Transposed-LDS (Vt[d][l], stride 40), plain ds_read_b128 fragments,
// per-chunk partials (no atomics), k_vkred sums.
__global__ __launch_bounds__(256) void k_vk(const unsigned short* __restrict__ vb,
                                            const unsigned short* __restrict__ kfb,
                                            float* __restrict__ part) {
  const int bh = blockIdx.x >> 4;
  const int chunk = blockIdx.x & 15;
  const int t = threadIdx.x;
  const int wv = t >> 6, lane = t & 63;
  const int quad = lane >> 4, m16 = lane & 15;

  __shared__ __align__(16) unsigned short Vt[64 * 40];
  __shared__ __align__(16) unsigned short Kt[64 * 40];
  __shared__ float dred[4][64];

  f32x4 acc[4] = {};
  float accD = 0.f;

  for (int tile = 0; tile < 8; ++tile) {
    const size_t rbase =
        ((size_t)bh * 4096 + chunk * 256 + tile * 32 + wv * 8) * 64 + lane;
    bf16x8 vv, kv;
#pragma unroll
    for (int j = 0; j < 8; ++j) {
      unsigned short ve = vb[rbase + j * 64];
      unsigned short ke = kfb[rbase + j * 64];
      vv[j] = (short)ve;
      kv[j] = (short)ke;
      accD += bf2f(ke);
    }
    *reinterpret_cast<bf16x8*>(Vt + lane * 40 + wv * 8) = vv;
    *reinterpret_cast<bf16x8*>(Kt + lane * 40 + wv * 8) = kv;
    __syncthreads();

    bf16x8 fa = *reinterpret_cast<const bf16x8*>(Vt + (wv * 16 + m16) * 40 + quad * 8);
#pragma unroll
    for (int j = 0; j < 4; ++j) {
      bf16x8 fb = *reinterpret_cast<const bf16x8*>(Kt + (j * 16 + m16) * 40 + quad * 8);
      acc[j] = __builtin_amdgcn_mfma_f32_16x16x32_bf16(fa, fb, acc[j], 0, 0, 0);
    }
    __syncthreads();
  }

  float* dst = part + ((size_t)chunk * 64 + bh) * 4160;
#pragma unroll
  for (int j = 0; j < 4; ++j)
#pragma unroll
    for (int r = 0; r < 4; ++r)
      dst[(wv * 16 + quad * 4 + r) * 64 + j * 16 + m16] = acc[j][r];

  dred[wv][lane] = accD;
  __syncthreads();
  if (t < 64) dst[64 * 64 + t] = dred[0][t] + dred[1][t] + dred[2][t] + dred[3][t];
}

// ---------------- reduce 16 per-chunk partials -> vkbuf ----------------
__global__ __launch_bounds__(256) void k_vkred(const float* __restrict__ part,
                                               float* __restrict__ vk) {
  const int i = (blockIdx.x * 256 + threadIdx.x) * 4;  // 260*1024 == 266240 exact
  float4 s = *reinterpret_cast<const float4*>(part + i);
#pragma unroll
  for (int c = 1; c < 16; ++c) {
    float4 r = *reinterpret_cast<const float4*>(part + (size_t)c * 266240 + i);
    s.x += r.x; s.y += r.y; s.z += r.z; s.w += r.w;
  }
  *reinterpret_cast<float4*>(vk + i) = s;
}

// ---------------- res = qf . vk^T ; attn = res/(den+eps) -> bf16 BLD ----------------
__global__ __launch_bounds__(256) void k_res(const unsigned short* __restrict__ qfb,
                                             const float* __restrict__ vk,
                                             unsigned short* __restrict__ attnb) {
  const int bh = blockIdx.x >> 5;
  const int lt = (blockIdx.x & 31) << 7;
  const int b = bh >> 4, h = bh & 15;
  const int t = threadIdx.x;
  const int wave = t >> 6, lane = t & 63;
  __shared__ unsigned short Aq[128 * 64];
  __shared__ unsigned short Bv[64 * 64];
  __shared__ float vkD[64];
  __shared__ float invden[128];

  const unsigned short* Ag = qfb + ((size_t)bh * 4096 + lt) * 64;
#pragma unroll
  for (int s = 0; s < 4; ++s)
    stage16(Ag + wave * 2048 + s * 512 + lane * 8, Aq + wave * 2048 + s * 512, lane);

  const float* vsrc = vk + (size_t)bh * 65 * 64;
  {
    int base = t * 16;
#pragma unroll
    for (int c = 0; c < 4; ++c) {
      float4 f = *reinterpret_cast<const float4*>(vsrc + base + c * 4);
      ushort4 o = { f2bf(f.x), f2bf(f.y), f2bf(f.z), f2bf(f.w) };
      *reinterpret_cast<ushort4*>(Bv + base + c * 4) = o;
    }
  }
  if (t < 64) vkD[t] = vsrc[64 * 64 + t];
  __syncthreads();

  f32x4 acc[2][4] = {};
  const int quad = lane >> 4, m16 = lane & 15;
#pragma unroll
  for (int step = 0; step < 2; ++step) {
    bf16x8 fa[2], fb[4];
#pragma unroll
    for (int i = 0; i < 2; ++i)
      fa[i] = *reinterpret_cast<const bf16x8*>(Aq + (wave * 32 + i * 16 + m16) * 64 +
                                               step * 32 + quad * 8);
#pragma unroll
    for (int j = 0; j < 4; ++j)
      fb[j] = *reinterpret_cast<const bf16x8*>(Bv + (j * 16 + m16) * 64 +
                                               step * 32 + quad * 8);
#pragma unroll
    for (int i = 0; i < 2; ++i)
#pragma unroll
      for (int j = 0; j < 4; ++j)
        acc[i][j] = __builtin_amdgcn_mfma_f32_16x16x32_bf16(fa[i], fb[j], acc[i][j], 0, 0, 0);
  }

  {
    const unsigned short* qr = Aq + (t >> 1) * 64 + (t & 1) * 32;
    const float* vd = vkD + (t & 1) * 32;
    float ds = 0.f;
#pragma unroll
    for (int c = 0; c < 4; ++c) {
      bf16x8 qv = *reinterpret_cast<const bf16x8*>(qr + c * 8);
#pragma unroll
      for (int j = 0; j < 8; ++j)
        ds += bf2f((unsigned short)qv[j]) * vd[c * 8 + j];
    }
    ds += __shfl_xor(ds, 1, 64);
    if ((t & 1) == 0) invden[t >> 1] = 1.0f / (ds + EPS_LIN);
  }
  __syncthreads();

#pragma unroll
  for (int i = 0; i < 2; ++i) {
#pragma unroll
    for (int r = 0; r < 4; ++r) {
      int row = wave * 32 + i * 16 + quad * 4 + r;
      float inv = invden[row];
      unsigned short* dst = attnb + ((size_t)(b * 4096 + lt + row)) * 1024 + h * 64;
#pragma unroll
      for (int j = 0; j < 4; ++j)
        dst[j * 16 + m16] = f2bf(acc[i][j][r] * inv);
    }
  }
}

// ---------------- final rmsnorm (wave-per-row, 16 elems/lane) ----------------
__global__ __launch_bounds__(256) void k_outnorm(const unsigned short* __restrict__ preb,
                                                 const float* __restrict__ gout,
                                                 float* __restrict__ out) {
  const int row = (blockIdx.x << 2) + (threadIdx.x >> 6);
  const int lane = threadIdx.x & 63;
  const unsigned short* src = preb + (size_t)row * 1024 + lane * 16;
  float* drow = out + (size_t)row * 1024 + lane * 16;
  bf16x8 a0 = *reinterpret_cast<const bf16x8*>(src);
  bf16x8 a1 = *reinterpret_cast<const bf16x8*>(src + 8);
  float v[16];
  float ss = 0.f;
#pragma unroll
  for (int e = 0; e < 8; ++e) {
    v[e] = bf2f((unsigned short)a0[e]);
    v[8 + e] = bf2f((unsigned short)a1[e]);
  }
#pragma unroll
  for (int e = 0; e < 16; ++e) ss += v[e] * v[e];
#pragma unroll
  for (int off = 1; off < 64; off <<= 1) ss += __shfl_xor(ss, off, 64);
  const float sc = rsqrtf(ss * (1.0f / 1024.0f) + RMS_EPS);
  const float* gp = gout + lane * 16;
#pragma unroll
  for (int c = 0; c < 4; ++c) {
    float4 o = { v[c * 4 + 0] * sc * gp[c * 4 + 0], v[c * 4 + 1] * sc * gp[c * 4 + 1],
                 v[c * 4 + 2] * sc * gp[c * 4 + 2], v[c * 4 + 3] * sc * gp[c * 4 + 3] };
    *reinterpret_cast<float4*>(drow + c * 4) = o;
  }
}

// ---------------- workspace layout (bytes) ----------------
#define OFF_XB     0ull
#define OFF_WQKVB  33554432ull
#define OFF_WOUTB  39845888ull
#define OFF_QB     41943040ull
#define OFF_KB     75497472ull
#define OFF_VB     109051904ull
#define OFF_QFB    142606336ull
#define OFF_KFB    176160768ull
#define OFF_VK     209715200ull
#define OFF_ATTNB  210780160ull
#define OFF_COST   244334592ull
#define OFF_SINT   244858880ull
#define WS_NEEDED  245383168ull
// xb region unused since R10 (x read directly as f32 by QKV GEMM)
// preb (bf16, 32MB) aliases OFF_QB (qb dead by then)
// vkpart (f32, 17MB) aliases OFF_ATTNB (consumed by k_vkred before k_res writes attnb)

extern "C" void kernel_launch(void* const* d_in, const int* in_sizes, int n_in,
                              void* d_out, int out_size, void* d_ws, size_t ws_size,
                              hipStream_t stream) {
  const float* x    = (const float*)d_in[0];
  const float* Wqkv = (const float*)d_in[1];
  const float* bqkv = (const float*)d_in[2];
  const float* gq   = (const float*)d_in[3];
  const float* gk   = (const float*)d_in[4];
  const float* Wout = (const float*)d_in[5];
  const float* bout = (const float*)d_in[6];
  const float* gout = (const float*)d_in[7];

  if (ws_size < WS_NEEDED) return;

  char* ws = (char*)d_ws;
  unsigned short* wqkvb = (unsigned short*)(ws + OFF_WQKVB);
  unsigned short* woutb = (unsigned short*)(ws + OFF_WOUTB);
  unsigned short* qb    = (unsigned short*)(ws + OFF_QB);
  unsigned short* kb    = (unsigned short*)(ws + OFF_KB);
  unsigned short* vb    = (unsigned short*)(ws + OFF_VB);
  unsigned short* qfb   = (unsigned short*)(ws + OFF_QFB);
  unsigned short* kfb   = (unsigned short*)(ws + OFF_KFB);
  float*          vkbuf = (float*)(ws + OFF_VK);
  unsigned short* attnb = (unsigned short*)(ws + OFF_ATTNB);
  float*          cosT  = (float*)(ws + OFF_COST);
  float*          sinT  = (float*)(ws + OFF_SINT);
  unsigned short* preb  = (unsigned short*)(ws + OFF_QB);   // alias
  float*          vkpart = (float*)(ws + OFF_ATTNB);        // alias

  // fused init: weight conversions + rope table
  k_init<<<4608, 256, 0, stream>>>(Wqkv, Wout, wqkvb, woutb, cosT, sinT);

  // QKV gemm: M=16384 N=3072 K=1024, A = f32 x read directly
  k_gemm_bt<<<128 * 24, 256, 0, stream>>>(x, nullptr, wqkvb, bqkv, 16384, 3072, 1024, 0,
                                          qb, kb, vb, nullptr);
  k_qknorm<<<8192, 256, 0, stream>>>(qb, kb, gq, gk, cosT, sinT, qfb, kfb);

  // MFMA vk: 64 bh x 16 chunks, partials + reduce
  k_vk<<<1024, 256, 0, stream>>>(vb, kfb, vkpart);
  k_vkred<<<260, 256, 0, stream>>>(vkpart, vkbuf);

  k_res<<<2048, 256, 0, stream>>>(qfb, vkbuf, attnb);

  // out gemm: M=16384 N=1024 K=1024 -> preb (bf16, aliases qb region)
  k_gemm_bt<<<128 * 8, 256, 0, stream>>>(nullptr, attnb, woutb, bout, 16384, 1024, 1024, 1,
                                         nullptr, nullptr, nullptr, preb);
  k_outnorm<<<4096, 256, 0, stream>>>(preb, gout, (float*)d_out);
}

// Round 6
// 369.595 us; speedup vs baseline: 1.1858x; 1.1858x over previous
//
#include <hip/hip_runtime.h>
#include <stdint.h>

#define RMS_EPS 1.1920929e-07f
#define EPS_LIN 1e-6f

typedef __attribute__((ext_vector_type(8))) short bf16x8;
typedef __attribute__((ext_vector_type(4))) float f32x4;

__device__ __forceinline__ unsigned short f2bf(float f) {
  union { float f; unsigned int u; } v; v.f = f;
  unsigned int r = v.u + 0x7fffu + ((v.u >> 16) & 1u);
  return (unsigned short)(r >> 16);
}
__device__ __forceinline__ float bf2f(unsigned short s) {
  union { unsigned int u; float f; } v; v.u = ((unsigned int)s) << 16;
  return v.f;
}

// ---------------- fused init: f32->bf16 x3 + rope table ----------------
// R11: back to R8 form (x IS converted to bf16 — R10 proved direct-f32-A
// breaks the staging pipeline: FETCH 143->277MB, MfmaUtil 41->21%).
// block partition: [0,16384) x | [16384,19456) Wqkv | [19456,20480) Wout |
//                  [20480,20992) rope  (vkbuf zero dropped: k_vkred overwrites)
__global__ __launch_bounds__(256) void k_init(
    const float* __restrict__ x, const float* __restrict__ Wqkv,
    const float* __restrict__ Wout,
    unsigned short* __restrict__ xb, unsigned short* __restrict__ wqkvb,
    unsigned short* __restrict__ woutb,
    float* __restrict__ cosT, float* __restrict__ sinT) {
  const int blk = blockIdx.x;
  const int t = threadIdx.x;
  if (blk < 20480) {
    const float* src;
    unsigned short* dst;
    int base;
    if (blk < 16384) { src = x; dst = xb; base = blk; }
    else if (blk < 19456) { src = Wqkv; dst = wqkvb; base = blk - 16384; }
    else { src = Wout; dst = woutb; base = blk - 19456; }
    int i = (base * 256 + t) * 4;
    float4 v = *reinterpret_cast<const float4*>(src + i);
    ushort4 o = { f2bf(v.x), f2bf(v.y), f2bf(v.z), f2bf(v.w) };
    *reinterpret_cast<ushort4*>(dst + i) = o;
  } else {
    int idx = (blk - 20480) * 256 + t;
    int l = idx >> 5, i = idx & 31;
    float inv_freq = expf(-((float)(2 * i) / 64.0f) * logf(10000.0f));
    float ang = (float)l * inv_freq;
    cosT[idx] = cosf(ang);
    sinT[idx] = sinf(ang);
  }
}

// ---------------- async global->LDS 16B stage ----------------
__device__ __forceinline__ void stage16(const unsigned short* g, unsigned short* lds_base,
                                        int lane) {
#if __has_builtin(__builtin_amdgcn_global_load_lds)
  __builtin_amdgcn_global_load_lds(
      (const __attribute__((address_space(1))) unsigned int*)g,
      (__attribute__((address_space(3))) unsigned int*)lds_base, 16, 0, 0);
#else
  *reinterpret_cast<uint4*>(lds_base + lane * 8) = *reinterpret_cast<const uint4*>(g);
#endif
}

// ---------------- bf16 GEMM C = A(MxK) * B(NxK)^T + bias ----------------
// 128x128 tile, BK=64, XOR-swizzled LDS (0 conflicts, ~918 TF), gload_lds
// staging — the R8-verified structure. R11's ONLY change: launch_bounds
// (256,3)->(256,4): 4 blocks/CU (LDS 128<=160KB; regs 60V+64A=124<=128/wave),
// 16 waves/CU vs 12 to hide the per-K-step vmcnt(0)+barrier drain; also makes
// QKV grid 3072 = 3.0 exact rounds and out-GEMM 1024 = 1.0 exact round.
__global__ __launch_bounds__(256, 4) void k_gemm_bt(
    const unsigned short* __restrict__ A, const unsigned short* __restrict__ Bw,
    const float* __restrict__ bias, int M, int N, int K, int mode,
    unsigned short* __restrict__ qb, unsigned short* __restrict__ kb,
    unsigned short* __restrict__ vb, unsigned short* __restrict__ preb) {
  __shared__ unsigned short As[128 * 64];
  __shared__ unsigned short Bs[128 * 64];
  const int nt = N >> 7;
  const int bm = blockIdx.x / nt, bn = blockIdx.x % nt;
  const int m0 = bm << 7, n0 = bn << 7;
  const int t = threadIdx.x;
  const int wave = t >> 6, lane = t & 63;
  const int wr = wave >> 1, wc = wave & 1;
  const int quad = lane >> 4, m16 = lane & 15;

  const unsigned short* ApS[4];
  const unsigned short* BpS[4];
  unsigned short* AlS[4];
  unsigned short* BlS[4];
#pragma unroll
  for (int s = 0; s < 4; ++s) {
    int u = wave * 256 + s * 64 + lane;
    int row = u >> 3;
    int ku = (u & 7) ^ (row & 7);
    ApS[s] = A + (size_t)(m0 + row) * K + ku * 8;
    BpS[s] = Bw + (size_t)(n0 + row) * K + ku * 8;
    AlS[s] = As + (size_t)(wave * 256 + s * 64) * 8;
    BlS[s] = Bs + (size_t)(wave * 256 + s * 64) * 8;
  }

  int offA[4][2], offB[4][2];
#pragma unroll
  for (int i = 0; i < 4; ++i) {
    int rowA = wr * 64 + i * 16 + m16;
    int rowB = wc * 64 + i * 16 + m16;
#pragma unroll
    for (int ks = 0; ks < 2; ++ks) {
      int kuf = ks * 4 + quad;
      offA[i][ks] = (rowA * 8 + (kuf ^ (rowA & 7))) * 8;
      offB[i][ks] = (rowB * 8 + (kuf ^ (rowB & 7))) * 8;
    }
  }

  f32x4 acc[4][4] = {};

  for (int k0 = 0; k0 < K; k0 += 64) {
#pragma unroll
    for (int s = 0; s < 4; ++s) {
      stage16(ApS[s] + k0, AlS[s], lane);
      stage16(BpS[s] + k0, BlS[s], lane);
    }
    __syncthreads();
#pragma unroll
    for (int ks = 0; ks < 2; ++ks) {
      bf16x8 fa[4], fb[4];
#pragma unroll
      for (int i = 0; i < 4; ++i)
        fa[i] = *reinterpret_cast<const bf16x8*>(As + offA[i][ks]);
#pragma unroll
      for (int j = 0; j < 4; ++j)
        fb[j] = *reinterpret_cast<const bf16x8*>(Bs + offB[j][ks]);
#pragma unroll
      for (int i = 0; i < 4; ++i)
#pragma unroll
        for (int j = 0; j < 4; ++j)
          acc[i][j] = __builtin_amdgcn_mfma_f32_16x16x32_bf16(fa[i], fb[j], acc[i][j], 0, 0, 0);
    }
    __syncthreads();
  }

#pragma unroll
  for (int i = 0; i < 4; ++i) {
    int rbase = m0 + wr * 64 + i * 16 + quad * 4;
#pragma unroll
    for (int j = 0; j < 4; ++j) {
      int col = n0 + wc * 64 + j * 16 + m16;
      float bc = bias[col];
#pragma unroll
      for (int r = 0; r < 4; ++r) {
        int row = rbase + r;
        float val = acc[i][j][r] + bc;
        unsigned short bv = f2bf(val);
        if (mode == 0) {
          if (col < 1024) {
            qb[(size_t)row * 1024 + col] = bv;
          } else if (col < 2048) {
            kb[(size_t)row * 1024 + (col - 1024)] = bv;
          } else {
            int h = (col - 2048) >> 6, d = col & 63;
            int b = row >> 12, l = row & 4095;
            vb[(((size_t)(b * 16 + h)) * 4096 + l) * 64 + d] = bv;
          }
        } else {
          preb[(size_t)row * N + col] = bv;
        }
      }
    }
  }
}

// ---------------- q/k rmsnorm + rope + relu (wave-per-row) ----------
// 16 contiguous elems per lane -> 2x b128 load + 2x b128 store per array.
__global__ __launch_bounds__(256) void k_qknorm(
    const unsigned short* __restrict__ qb, const unsigned short* __restrict__ kb,
    const float* __restrict__ gq, const float* __restrict__ gk,
    const float* __restrict__ cosT, const float* __restrict__ sinT,
    unsigned short* __restrict__ qfb, unsigned short* __restrict__ kfb) {
  const int wid = (blockIdx.x << 2) + (threadIdx.x >> 6);
  const int row = wid >> 1;
  const int which = wid & 1;
  const int lane = threadIdx.x & 63;
  const int l = row & 4095;
  const int b = row >> 12;
  const unsigned short* src = (which ? kb : qb) + (size_t)row * 1024 + lane * 16;
  const float* g = which ? gk : gq;
  unsigned short* dstb = which ? kfb : qfb;

  bf16x8 u0 = *reinterpret_cast<const bf16x8*>(src);
  bf16x8 u1 = *reinterpret_cast<const bf16x8*>(src + 8);
  float v[16];
  float ss = 0.f;
#pragma unroll
  for (int e = 0; e < 8; ++e) {
    v[e] = bf2f((unsigned short)u0[e]);
    v[8 + e] = bf2f((unsigned short)u1[e]);
  }
#pragma unroll
  for (int e = 0; e < 16; ++e) ss += v[e] * v[e];
#pragma unroll
  for (int off = 1; off < 64; off <<= 1) ss += __shfl_xor(ss, off, 64);
  const float sc = rsqrtf(ss * (1.0f / 1024.0f) + RMS_EPS);

  const float* gp = g + lane * 16;
  const float* cp = cosT + l * 32 + (lane & 3) * 8;
  const float* sp = sinT + l * 32 + (lane & 3) * 8;
  bf16x8 o0, o1;
#pragma unroll
  for (int p = 0; p < 8; ++p) {
    float cc = cp[p], sv = sp[p];
    float x0 = v[2 * p] * sc * gp[2 * p];
    float x1 = v[2 * p + 1] * sc * gp[2 * p + 1];
    float r0 = x0 * cc - x1 * sv;
    float r1 = x0 * sv + x1 * cc;
    unsigned short b0 = f2bf(fmaxf(r0, 0.f));
    unsigned short b1 = f2bf(fmaxf(r1, 0.f));
    if (p < 4) { o0[2 * p] = (short)b0; o0[2 * p + 1] = (short)b1; }
    else { o1[2 * (p - 4)] = (short)b0; o1[2 * (p - 4) + 1] = (short)b1; }
  }
  unsigned short* dp =
      dstb + (((size_t)(b * 16 + (lane >> 2))) * 4096 + l) * 64 + (lane & 3) * 16;
  *reinterpret_cast<bf16x8*>(dp) = o0;
  *reinterpret_cast<bf16x8*>(dp + 8) = o1;
}

// ---------------- vk[p][d] = sum_l vpad[l][p]*kf[l][d] (per bh) -- MFMA ----------
// Transposed-LDS (Vt[d][l], stride 40), plain ds_read_b128 fragments,
// per-chunk partials (no atomics), k_vkred sums. R8-verified, unchanged.
__global__ __launch_bounds__(256) void k_vk(const unsigned short* __restrict__ vb,
                                            const unsigned short* __restrict__ kfb,
                                            float* __restrict__ part) {
  const int bh = blockIdx.x >> 4;
  const int chunk = blockIdx.x & 15;
  const int t = threadIdx.x;
  const int wv = t >> 6, lane = t & 63;
  const int quad = lane >> 4, m16 = lane & 15;

  __shared__ __align__(16) unsigned short Vt[64 * 40];
  __shared__ __align__(16) unsigned short Kt[64 * 40];
  __shared__ float dred[4][64];

  f32x4 acc[4] = {};
  float accD = 0.f;

  for (int tile = 0; tile < 8; ++tile) {
    const size_t rbase =
        ((size_t)bh * 4096 + chunk * 256 + tile * 32 + wv * 8) * 64 + lane;
    bf16x8 vv, kv;
#pragma unroll
    for (int j = 0; j < 8; ++j) {
      unsigned short ve = vb[rbase + j * 64];
      unsigned short ke = kfb[rbase + j * 64];
      vv[j] = (short)ve;
      kv[j] = (short)ke;
      accD += bf2f(ke);
    }
    *reinterpret_cast<bf16x8*>(Vt + lane * 40 + wv * 8) = vv;
    *reinterpret_cast<bf16x8*>(Kt + lane * 40 + wv * 8) = kv;
    __syncthreads();

    bf16x8 fa = *reinterpret_cast<const bf16x8*>(Vt + (wv * 16 + m16) * 40 + quad * 8);
#pragma unroll
    for (int j = 0; j < 4; ++j) {
      bf16x8 fb = *reinterpret_cast<const bf16x8*>(Kt + (j * 16 + m16) * 40 + quad * 8);
      acc[j] = __builtin_amdgcn_mfma_f32_16x16x32_bf16(fa, fb, acc[j], 0, 0, 0);
    }
    __syncthreads();
  }

  float* dst = part + ((size_t)chunk * 64 + bh) * 4160;
#pragma unroll
  for (int j = 0; j < 4; ++j)
#pragma unroll
    for (int r = 0; r < 4; ++r)
      dst[(wv * 16 + quad * 4 + r) * 64 + j * 16 + m16] = acc[j][r];

  dred[wv][lane] = accD;
  __syncthreads();
  if (t < 64) dst[64 * 64 + t] = dred[0][t] + dred[1][t] + dred[2][t] + dred[3][t];
}

// ---------------- reduce 16 per-chunk partials -> vkbuf ----------------
__global__ __launch_bounds__(256) void k_vkred(const float* __restrict__ part,
                                               float* __restrict__ vk) {
  const int i = (blockIdx.x * 256 + threadIdx.x) * 4;  // 260*1024 == 266240 exact
  float4 s = *reinterpret_cast<const float4*>(part + i);
#pragma unroll
  for (int c = 1; c < 16; ++c) {
    float4 r = *reinterpret_cast<const float4*>(part + (size_t)c * 266240 + i);
    s.x += r.x; s.y += r.y; s.z += r.z; s.w += r.w;
  }
  *reinterpret_cast<float4*>(vk + i) = s;
}

// ---------------- res = qf . vk^T ; attn = res/(den+eps) -> bf16 BLD ----------------
__global__ __launch_bounds__(256) void k_res(const unsigned short* __restrict__ qfb,
                                             const float* __restrict__ vk,
                                             unsigned short* __restrict__ attnb) {
  const int bh = blockIdx.x >> 5;
  const int lt = (blockIdx.x & 31) << 7;
  const int b = bh >> 4, h = bh & 15;
  const int t = threadIdx.x;
  const int wave = t >> 6, lane = t & 63;
  __shared__ unsigned short Aq[128 * 64];
  __shared__ unsigned short Bv[64 * 64];
  __shared__ float vkD[64];
  __shared__ float invden[128];

  const unsigned short* Ag = qfb + ((size_t)bh * 4096 + lt) * 64;
#pragma unroll
  for (int s = 0; s < 4; ++s)
    stage16(Ag + wave * 2048 + s * 512 + lane * 8, Aq + wave * 2048 + s * 512, lane);

  const float* vsrc = vk + (size_t)bh * 65 * 64;
  {
    int base = t * 16;
#pragma unroll
    for (int c = 0; c < 4; ++c) {
      float4 f = *reinterpret_cast<const float4*>(vsrc + base + c * 4);
      ushort4 o = { f2bf(f.x), f2bf(f.y), f2bf(f.z), f2bf(f.w) };
      *reinterpret_cast<ushort4*>(Bv + base + c * 4) = o;
    }
  }
  if (t < 64) vkD[t] = vsrc[64 * 64 + t];
  __syncthreads();

  f32x4 acc[2][4] = {};
  const int quad = lane >> 4, m16 = lane & 15;
#pragma unroll
  for (int step = 0; step < 2; ++step) {
    bf16x8 fa[2], fb[4];
#pragma unroll
    for (int i = 0; i < 2; ++i)
      fa[i] = *reinterpret_cast<const bf16x8*>(Aq + (wave * 32 + i * 16 + m16) * 64 +
                                               step * 32 + quad * 8);
#pragma unroll
    for (int j = 0; j < 4; ++j)
      fb[j] = *reinterpret_cast<const bf16x8*>(Bv + (j * 16 + m16) * 64 +
                                               step * 32 + quad * 8);
#pragma unroll
    for (int i = 0; i < 2; ++i)
#pragma unroll
      for (int j = 0; j < 4; ++j)
        acc[i][j] = __builtin_amdgcn_mfma_f32_16x16x32_bf16(fa[i], fb[j], acc[i][j], 0, 0, 0);
  }

  {
    const unsigned short* qr = Aq + (t >> 1) * 64 + (t & 1) * 32;
    const float* vd = vkD + (t & 1) * 32;
    float ds = 0.f;
#pragma unroll
    for (int c = 0; c < 4; ++c) {
      bf16x8 qv = *reinterpret_cast<const bf16x8*>(qr + c * 8);
#pragma unroll
      for (int j = 0; j < 8; ++j)
        ds += bf2f((unsigned short)qv[j]) * vd[c * 8 + j];
    }
    ds += __shfl_xor(ds, 1, 64);
    if ((t & 1) == 0) invden[t >> 1] = 1.0f / (ds + EPS_LIN);
  }
  __syncthreads();

#pragma unroll
  for (int i = 0; i < 2; ++i) {
#pragma unroll
    for (int r = 0; r < 4; ++r) {
      int row = wave * 32 + i * 16 + quad * 4 + r;
      float inv = invden[row];
      unsigned short* dst = attnb + ((size_t)(b * 4096 + lt + row)) * 1024 + h * 64;
#pragma unroll
      for (int j = 0; j < 4; ++j)
        dst[j * 16 + m16] = f2bf(acc[i][j][r] * inv);
    }
  }
}

// ---------------- final rmsnorm (wave-per-row, 16 elems/lane) ----------------
__global__ __launch_bounds__(256) void k_outnorm(const unsigned short* __restrict__ preb,
                                                 const float* __restrict__ gout,
                                                 float* __restrict__ out) {
  const int row = (blockIdx.x << 2) + (threadIdx.x >> 6);
  const int lane = threadIdx.x & 63;
  const unsigned short* src = preb + (size_t)row * 1024 + lane * 16;
  float* drow = out + (size_t)row * 1024 + lane * 16;
  bf16x8 a0 = *reinterpret_cast<const bf16x8*>(src);
  bf16x8 a1 = *reinterpret_cast<const bf16x8*>(src + 8);
  float v[16];
  float ss = 0.f;
#pragma unroll
  for (int e = 0; e < 8; ++e) {
    v[e] = bf2f((unsigned short)a0[e]);
    v[8 + e] = bf2f((unsigned short)a1[e]);
  }
#pragma unroll
  for (int e = 0; e < 16; ++e) ss += v[e] * v[e];
#pragma unroll
  for (int off = 1; off < 64; off <<= 1) ss += __shfl_xor(ss, off, 64);
  const float sc = rsqrtf(ss * (1.0f / 1024.0f) + RMS_EPS);
  const float* gp = gout + lane * 16;
#pragma unroll
  for (int c = 0; c < 4; ++c) {
    float4 o = { v[c * 4 + 0] * sc * gp[c * 4 + 0], v[c * 4 + 1] * sc * gp[c * 4 + 1],
                 v[c * 4 + 2] * sc * gp[c * 4 + 2], v[c * 4 + 3] * sc * gp[c * 4 + 3] };
    *reinterpret_cast<float4*>(drow + c * 4) = o;
  }
}

// ---------------- workspace layout (bytes) ----------------
#define OFF_XB     0ull
#define OFF_WQKVB  33554432ull
#define OFF_WOUTB  39845888ull
#define OFF_QB     41943040ull
#define OFF_KB     75497472ull
#define OFF_VB     109051904ull
#define OFF_QFB    142606336ull
#define OFF_KFB    176160768ull
#define OFF_VK     209715200ull
#define OFF_ATTNB  210780160ull
#define OFF_COST   244334592ull
#define OFF_SINT   244858880ull
#define WS_NEEDED  245383168ull
// preb (bf16, 32MB) aliases OFF_QB (qb dead by then)
// vkpart (f32, 17MB) aliases OFF_ATTNB (consumed by k_vkred before k_res writes attnb)

extern "C" void kernel_launch(void* const* d_in, const int* in_sizes, int n_in,
                              void* d_out, int out_size, void* d_ws, size_t ws_size,
                              hipStream_t stream) {
  const float* x    = (const float*)d_in[0];
  const float* Wqkv = (const float*)d_in[1];
  const float* bqkv = (const float*)d_in[2];
  const float* gq   = (const float*)d_in[3];
  const float* gk   = (const float*)d_in[4];
  const float* Wout = (const float*)d_in[5];
  const float* bout = (const float*)d_in[6];
  const float* gout = (const float*)d_in[7];

  if (ws_size < WS_NEEDED) return;

  char* ws = (char*)d_ws;
  unsigned short* xb    = (unsigned short*)(ws + OFF_XB);
  unsigned short* wqkvb = (unsigned short*)(ws + OFF_WQKVB);
  unsigned short* woutb = (unsigned short*)(ws + OFF_WOUTB);
  unsigned short* qb    = (unsigned short*)(ws + OFF_QB);
  unsigned short* kb    = (unsigned short*)(ws + OFF_KB);
  unsigned short* vb    = (unsigned short*)(ws + OFF_VB);
  unsigned short* qfb   = (unsigned short*)(ws + OFF_QFB);
  unsigned short* kfb   = (unsigned short*)(ws + OFF_KFB);
  float*          vkbuf = (float*)(ws + OFF_VK);
  unsigned short* attnb = (unsigned short*)(ws + OFF_ATTNB);
  float*          cosT  = (float*)(ws + OFF_COST);
  float*          sinT  = (float*)(ws + OFF_SINT);
  unsigned short* preb  = (unsigned short*)(ws + OFF_QB);   // alias
  float*          vkpart = (float*)(ws + OFF_ATTNB);        // alias

  // fused init: conversions + rope table
  k_init<<<20992, 256, 0, stream>>>(x, Wqkv, Wout, xb, wqkvb, woutb, cosT, sinT);

  // QKV gemm: M=16384 N=3072 K=1024
  k_gemm_bt<<<128 * 24, 256, 0, stream>>>(xb, wqkvb, bqkv, 16384, 3072, 1024, 0,
                                          qb, kb, vb, nullptr);
  k_qknorm<<<8192, 256, 0, stream>>>(qb, kb, gq, gk, cosT, sinT, qfb, kfb);

  // MFMA vk: 64 bh x 16 chunks, partials + reduce
  k_vk<<<1024, 256, 0, stream>>>(vb, kfb, vkpart);
  k_vkred<<<260, 256, 0, stream>>>(vkpart, vkbuf);

  k_res<<<2048, 256, 0, stream>>>(qfb, vkbuf, attnb);

  // out gemm: M=16384 N=1024 K=1024 -> preb (bf16, aliases qb region)
  k_gemm_bt<<<128 * 8, 256, 0, stream>>>(attnb, woutb, bout, 16384, 1024, 1024, 1,
                                         nullptr, nullptr, nullptr, preb);
  k_outnorm<<<4096, 256, 0, stream>>>(preb, gout, (float*)d_out);
}